// Round 4
// baseline (611.276 us; speedup 1.0000x reference)
//
#include <hip/hip_runtime.h>
#include <stdint.h>

#define N_ATOMS 100000
#define NS 4
#define NE 8
#define D0 384
#define D1 160
#define D2 128
#define D3 96
#define BUCKET_CAP 32768

// ---- workspace layout (bytes) ----
#define IDX_OFF_B 256
#define IDX_CAP (NS*BUCKET_CAP)               // 131072 ints
#define W1B_OFF (IDX_OFF_B + IDX_CAP*4)
#define W1_TOT (NS*NE*D0*D1)
#define W2_TOT (NS*NE*D1*D2)
#define W3_TOT (NS*NE*D2*D3)
#define W2B_OFF (W1B_OFF + W1_TOT*2)
#define W3B_OFF (W2B_OFF + W2_TOT*2)

// blocks: 4 waves * 32 atoms = 128 atoms per block.
// nb = sum_s ceil(count_s/128) is always in [782, 785] (counts sum to 100000).
// phase 1 = 768 blocks (3 blocks/CU * 256 CU, LDS-limited), XCD-chunked.
// tail: remaining RT = nb-768 (<=17) blocks split into (block, e-pair) units.
#define P1BLOCKS 768
#define GRID_MLP (P1BLOCKS + 17*4)            // 836

typedef __attribute__((ext_vector_type(8))) _Float16 h8v;
typedef __attribute__((ext_vector_type(4))) float f4v;

typedef __attribute__((address_space(3))) unsigned int lds_uint;
typedef __attribute__((address_space(1))) const unsigned int glob_uint;

__device__ __forceinline__ void gll16(const unsigned short* gp, unsigned short* lp){
    // async global->LDS: per-lane global addr, wave-uniform LDS base (+lane*16 by HW)
    __builtin_amdgcn_global_load_lds((glob_uint*)gp, (lds_uint*)lp, 16, 0, 0);
}

__device__ __forceinline__ unsigned short f2h(float x){
    _Float16 h = (_Float16)x;
    return *(unsigned short*)&h;
}

// jax.nn.celu(x, 0.1) = x>0 ? x : 0.1*expm1(x/0.1)
__device__ __forceinline__ float celu01(float v){
    return v > 0.f ? v : 0.1f * (__expf(fminf(v, 0.f) * 10.f) - 1.f);
}

// byte offset into a swizzled X tile: XOR row-bits into the 16B-slot bits.
// balanced (conflict-free) for both b128 col-reads and u16 row-writes.
__device__ __forceinline__ int swzb(int row, int colByte, int strideB){
    return (row * strideB + colByte) ^ ((row & 7) << 4);
}

__global__ void k_init(int* hdr, float* out){
    int i = threadIdx.x;
    if (i < 32) hdr[i] = 0;
    if (i == 0) out[0] = 0.f;
}

__global__ __launch_bounds__(256) void k_scatter(const int* __restrict__ species,
                                                 int* __restrict__ hdr,
                                                 int* __restrict__ idx){
    __shared__ int lc[NS];
    __shared__ int lb[NS];
    int tid = threadIdx.x;
    if (tid < NS) lc[tid] = 0;
    __syncthreads();
    int i = blockIdx.x * 256 + tid;
    int s = 0, r = 0;
    bool valid = (i < N_ATOMS);
    if (valid){
        s = species[i];
        r = atomicAdd(&lc[s], 1);
    }
    __syncthreads();
    if (tid < NS) lb[tid] = atomicAdd(&hdr[tid], lc[tid]);
    __syncthreads();
    if (valid) idx[s * BUCKET_CAP + lb[s] + r] = i;
}

// W1..W3 fp32 -> fp16 in MFMA-B-fragment order: [net][nt][kt][lane][j]
__global__ void k_convert(const float* __restrict__ W1, const float* __restrict__ W2,
                          const float* __restrict__ W3,
                          unsigned short* __restrict__ W1b, unsigned short* __restrict__ W2b,
                          unsigned short* __restrict__ W3b){
    int i = blockIdx.x * blockDim.x + threadIdx.x;
    if (i < W1_TOT){
        int net = i / (D0*D1);
        int r   = i % (D0*D1);
        int j = r & 7, lane = (r >> 3) & 63, kt = (r >> 9) % 12, nt = r / 6144;
        int k = kt*32 + (lane >> 4)*8 + j;
        int n = nt*16 + (lane & 15);
        W1b[i] = f2h(W1[(net*D0 + k)*D1 + n]);
    } else if (i < W1_TOT + W2_TOT){
        int i2 = i - W1_TOT;
        int net = i2 / (D1*D2);
        int r   = i2 % (D1*D2);
        int j = r & 7, lane = (r >> 3) & 63, kt = (r >> 9) % 5, nt = r / 2560;
        int k = kt*32 + (lane >> 4)*8 + j;
        int n = nt*16 + (lane & 15);
        W2b[i2] = f2h(W2[(net*D1 + k)*D2 + n]);
    } else if (i < W1_TOT + W2_TOT + W3_TOT){
        int i3 = i - W1_TOT - W2_TOT;
        int net = i3 / (D2*D3);
        int r   = i3 % (D2*D3);
        int j = r & 7, lane = (r >> 3) & 63, kt = (r >> 9) % 4, nt = r / 2048;
        int k = kt*32 + (lane >> 4)*8 + j;
        int n = nt*16 + (lane & 15);
        W3b[i3] = f2h(W3[(net*D2 + k)*D3 + n]);
    }
}

// Lockstep MLP: block = 4 waves = 128 atoms of ONE species. Weight strips are
// staged in LDS once per block (global_load_lds, double-buffered) and shared
// by all 4 waves -> 4x less L2 weight traffic, B-regs freed (no spill).
// X1/X2 live per-wave in one swizzled LDS region (natural strides + XOR).
__global__ __launch_bounds__(256, 3) void k_mlp(
    const float* __restrict__ aev, const int* __restrict__ hdr, const int* __restrict__ idx,
    const unsigned short* __restrict__ W1b, const unsigned short* __restrict__ W2b,
    const unsigned short* __restrict__ W3b,
    const float* __restrict__ b1, const float* __restrict__ b2, const float* __restrict__ b3,
    const float* __restrict__ W4, const float* __restrict__ b4, float* __restrict__ out)
{
    __shared__ __align__(128) unsigned short sX[4][5120];   // 40960 B, per-wave X1/X2 union (swizzled)
    __shared__ __align__(128) unsigned short stg[2][3072];  // 12288 B, weight-strip double buffer

    int tid = threadIdx.x;
    int lane = tid & 63, wid = tid >> 6;

    // ---- block -> (species, atom range, e range); k_scan folded in ----
    int c0 = hdr[0], c1 = hdr[1], c2 = hdr[2], c3 = hdr[3];
    int n0 = (c0 + 127) >> 7, n1 = (c1 + 127) >> 7, n2 = (c2 + 127) >> 7, n3 = (c3 + 127) >> 7;
    int p1 = n0, p2 = p1 + n1, p3 = p2 + n2, nb = p3 + n3;   // nb in [782,785]

    int g, eBeg, eEnd;
    if (blockIdx.x < P1BLOCKS){
        // bijective XCD-chunk map over exactly 768 blocks (96 per XCD class)
        g = (blockIdx.x & 7) * 96 + (blockIdx.x >> 3);
        eBeg = 0; eEnd = NE;
    } else {
        int RT = nb - P1BLOCKS;                               // <= 17
        int u = blockIdx.x - P1BLOCKS;
        if (u >= RT * 4) return;                              // block-uniform exit
        g = P1BLOCKS + (u >> 2);
        eBeg = (u & 3) * 2; eEnd = eBeg + 2;
    }

    int s   = (g >= p3) ? 3 : (g >= p2) ? 2 : (g >= p1) ? 1 : 0;
    int blk = g - (s == 0 ? 0 : s == 1 ? p1 : s == 2 ? p2 : p3);
    int cs  = (s == 0 ? c0 : s == 1 ? c1 : s == 2 ? c2 : c3);
    int base = blk * 128 + wid * 32;
    int nValid = cs - base; if (nValid > 32) nValid = 32; if (nValid < 0) nValid = 0;
    const int* myIdx = idx + s * BUCKET_CAP + base;

    int m = lane & 15, quad = lane >> 4;
    char* xb = (char*)sX[wid];

    // ---- layer-1 A fragments from global AEV (fp32->fp16), e-invariant, NT loads ----
    h8v A1[2][12];
    #pragma unroll
    for (int mt = 0; mt < 2; mt++){
        int slot = mt*16 + m;
        int atom = 0;
        if (nValid > 0) atom = myIdx[slot < nValid ? slot : nValid - 1];
        const float* ap = aev + (size_t)atom * D0 + quad*8;
        #pragma unroll
        for (int kt = 0; kt < 12; kt++){
            f4v u = __builtin_nontemporal_load((const f4v*)(ap + kt*32));
            f4v v = __builtin_nontemporal_load((const f4v*)(ap + kt*32 + 4));
            h8v f;
            f[0] = (_Float16)u.x; f[1] = (_Float16)u.y; f[2] = (_Float16)u.z; f[3] = (_Float16)u.w;
            f[4] = (_Float16)v.x; f[5] = (_Float16)v.y; f[6] = (_Float16)v.z; f[7] = (_Float16)v.w;
            A1[mt][kt] = f;
        }
    }

    float e0[4] = {0.f,0.f,0.f,0.f};
    float e1[4] = {0.f,0.f,0.f,0.f};

    // stage P 1024-byte pieces, cooperatively across the 4 waves
    #define STAGE(P, src, dst) \
        for (int p = wid; p < (P); p += 4) gll16((src) + p*512 + lane*8, (dst) + p*512);

    #pragma unroll 1
    for (int e = eBeg; e < eEnd; e++){
        int net = s * NE + e;

        // ---------- layer 1: A1(regs) [K=384] -> X1 [N=160], 20 half-strip chunks ----------
        {
            const unsigned short* w1 = W1b + (size_t)net * (D0*D1);
            STAGE(6, w1, stg[0]);
            __syncthreads();
            #pragma unroll 1
            for (int nt = 0; nt < 10; nt++){
                // chunk 2nt (half 0) in stg[0]; stage half 1
                STAGE(6, w1 + (2*nt + 1)*3072, stg[1]);
                float bi1 = b1[net*D1 + nt*16 + m];
                f4v a0e = {bi1, bi1, bi1, bi1}, a1e = a0e;
                f4v a0o = {0.f,0.f,0.f,0.f},   a1o = a0o;
                #pragma unroll
                for (int k2 = 0; k2 < 6; k2++){
                    h8v B = *(const h8v*)&stg[0][k2*512 + lane*8];
                    if ((k2 & 1) == 0){
                        a0e = __builtin_amdgcn_mfma_f32_16x16x32_f16(A1[0][k2], B, a0e, 0, 0, 0);
                        a1e = __builtin_amdgcn_mfma_f32_16x16x32_f16(A1[1][k2], B, a1e, 0, 0, 0);
                    } else {
                        a0o = __builtin_amdgcn_mfma_f32_16x16x32_f16(A1[0][k2], B, a0o, 0, 0, 0);
                        a1o = __builtin_amdgcn_mfma_f32_16x16x32_f16(A1[1][k2], B, a1o, 0, 0, 0);
                    }
                }
                __syncthreads();
                // chunk 2nt+1 (half 1) in stg[1]; stage half 0 of nt+1
                if (nt < 9) STAGE(6, w1 + (2*nt + 2)*3072, stg[0]);
                #pragma unroll
                for (int k2 = 0; k2 < 6; k2++){
                    h8v B = *(const h8v*)&stg[1][k2*512 + lane*8];
                    if ((k2 & 1) == 0){
                        a0e = __builtin_amdgcn_mfma_f32_16x16x32_f16(A1[0][6+k2], B, a0e, 0, 0, 0);
                        a1e = __builtin_amdgcn_mfma_f32_16x16x32_f16(A1[1][6+k2], B, a1e, 0, 0, 0);
                    } else {
                        a0o = __builtin_amdgcn_mfma_f32_16x16x32_f16(A1[0][6+k2], B, a0o, 0, 0, 0);
                        a1o = __builtin_amdgcn_mfma_f32_16x16x32_f16(A1[1][6+k2], B, a1o, 0, 0, 0);
                    }
                }
                f4v a0 = a0e + a0o, a1 = a1e + a1o;
                int colB = (nt*16 + m)*2;
                #pragma unroll
                for (int r = 0; r < 4; r++){
                    *(unsigned short*)(xb + swzb(quad*4 + r,      colB, 320)) = f2h(celu01(a0[r]));
                    *(unsigned short*)(xb + swzb(16 + quad*4 + r, colB, 320)) = f2h(celu01(a1[r]));
                }
                __syncthreads();
            }
        }

        // ---------- layer 2: X1 [K=160] -> X2 [N=128], 8 strip chunks ----------
        {
            h8v A2[2][5];
            #pragma unroll
            for (int mt = 0; mt < 2; mt++)
                #pragma unroll
                for (int kt = 0; kt < 5; kt++)
                    A2[mt][kt] = *(const h8v*)(xb + swzb(mt*16 + m, (kt*32 + quad*8)*2, 320));
            const unsigned short* w2 = W2b + (size_t)net * (D1*D2);
            STAGE(5, w2, stg[0]);
            __syncthreads();
            #pragma unroll 1
            for (int nt = 0; nt < 8; nt++){
                int buf = nt & 1;
                if (nt < 7) STAGE(5, w2 + (nt + 1)*2560, stg[buf ^ 1]);
                float bi2 = b2[net*D2 + nt*16 + m];
                f4v a0e = {bi2, bi2, bi2, bi2}, a1e = a0e;
                f4v a0o = {0.f,0.f,0.f,0.f},   a1o = a0o;
                #pragma unroll
                for (int kt = 0; kt < 5; kt++){
                    h8v B = *(const h8v*)&stg[buf][kt*512 + lane*8];
                    if ((kt & 1) == 0){
                        a0e = __builtin_amdgcn_mfma_f32_16x16x32_f16(A2[0][kt], B, a0e, 0, 0, 0);
                        a1e = __builtin_amdgcn_mfma_f32_16x16x32_f16(A2[1][kt], B, a1e, 0, 0, 0);
                    } else {
                        a0o = __builtin_amdgcn_mfma_f32_16x16x32_f16(A2[0][kt], B, a0o, 0, 0, 0);
                        a1o = __builtin_amdgcn_mfma_f32_16x16x32_f16(A2[1][kt], B, a1o, 0, 0, 0);
                    }
                }
                f4v a0 = a0e + a0o, a1 = a1e + a1o;
                int colB = (nt*16 + m)*2;
                #pragma unroll
                for (int r = 0; r < 4; r++){
                    *(unsigned short*)(xb + swzb(quad*4 + r,      colB, 256)) = f2h(celu01(a0[r]));
                    *(unsigned short*)(xb + swzb(16 + quad*4 + r, colB, 256)) = f2h(celu01(a1[r]));
                }
                __syncthreads();
            }
        }

        // ---------- layer 3 + 4 fused: X2 [K=128] -> per-lane partial energies ----------
        {
            h8v A3[2][4];
            #pragma unroll
            for (int mt = 0; mt < 2; mt++)
                #pragma unroll
                for (int kt = 0; kt < 4; kt++)
                    A3[mt][kt] = *(const h8v*)(xb + swzb(mt*16 + m, (kt*32 + quad*8)*2, 256));
            const unsigned short* w3 = W3b + (size_t)net * (D2*D3);
            const float* w4 = W4 + net * D3;
            STAGE(4, w3, stg[0]);
            __syncthreads();
            #pragma unroll 1
            for (int nt = 0; nt < 6; nt++){
                int buf = nt & 1;
                if (nt < 5) STAGE(4, w3 + (nt + 1)*2048, stg[buf ^ 1]);
                float bi3 = b3[net*D3 + nt*16 + m];
                f4v a0e = {bi3, bi3, bi3, bi3}, a1e = a0e;
                f4v a0o = {0.f,0.f,0.f,0.f},   a1o = a0o;
                #pragma unroll
                for (int kt = 0; kt < 4; kt++){
                    h8v B = *(const h8v*)&stg[buf][kt*512 + lane*8];
                    if ((kt & 1) == 0){
                        a0e = __builtin_amdgcn_mfma_f32_16x16x32_f16(A3[0][kt], B, a0e, 0, 0, 0);
                        a1e = __builtin_amdgcn_mfma_f32_16x16x32_f16(A3[1][kt], B, a1e, 0, 0, 0);
                    } else {
                        a0o = __builtin_amdgcn_mfma_f32_16x16x32_f16(A3[0][kt], B, a0o, 0, 0, 0);
                        a1o = __builtin_amdgcn_mfma_f32_16x16x32_f16(A3[1][kt], B, a1o, 0, 0, 0);
                    }
                }
                f4v a0 = a0e + a0o, a1 = a1e + a1o;
                float w = w4[nt*16 + m];
                #pragma unroll
                for (int r = 0; r < 4; r++){
                    e0[r] = fmaf(celu01(a0[r]), w, e0[r]);
                    e1[r] = fmaf(celu01(a1[r]), w, e1[r]);
                }
                __syncthreads();
            }
        }
    }

    // ---- final: mask padded atoms, single 6-shuffle wave reduction, one atomic ----
    {
        float tot = 0.f;
        #pragma unroll
        for (int r = 0; r < 4; r++){
            tot += (quad*4 + r      < nValid) ? e0[r] : 0.f;
            tot += (16 + quad*4 + r < nValid) ? e1[r] : 0.f;
        }
        tot += __shfl_xor(tot, 1, 64);
        tot += __shfl_xor(tot, 2, 64);
        tot += __shfl_xor(tot, 4, 64);
        tot += __shfl_xor(tot, 8, 64);
        tot += __shfl_xor(tot, 16, 64);
        tot += __shfl_xor(tot, 32, 64);
        if (lane == 0 && nValid > 0){
            float sb4 = 0.f;
            for (int e = eBeg; e < eEnd; e++) sb4 += b4[s*NE + e];
            atomicAdd(out, (tot + (float)nValid * sb4) * 0.125f);
        }
    }
    #undef STAGE
}

extern "C" void kernel_launch(void* const* d_in, const int* in_sizes, int n_in,
                              void* d_out, int out_size, void* d_ws, size_t ws_size,
                              hipStream_t stream){
    const float* aev     = (const float*)d_in[0];
    const int*   species = (const int*)  d_in[1];
    const float* W1 = (const float*)d_in[2];
    const float* b1 = (const float*)d_in[3];
    const float* W2 = (const float*)d_in[4];
    const float* b2 = (const float*)d_in[5];
    const float* W3 = (const float*)d_in[6];
    const float* b3 = (const float*)d_in[7];
    const float* W4 = (const float*)d_in[8];
    const float* b4 = (const float*)d_in[9];
    float* out = (float*)d_out;

    int* hdr = (int*)d_ws;
    int* idx = (int*)((char*)d_ws + IDX_OFF_B);
    unsigned short* W1b = (unsigned short*)((char*)d_ws + W1B_OFF);
    unsigned short* W2b = (unsigned short*)((char*)d_ws + W2B_OFF);
    unsigned short* W3b = (unsigned short*)((char*)d_ws + W3B_OFF);

    k_init   <<<1, 64, 0, stream>>>(hdr, out);
    k_scatter<<<(N_ATOMS + 255)/256, 256, 0, stream>>>(species, hdr, idx);
    int convTot = W1_TOT + W2_TOT + W3_TOT;
    k_convert<<<(convTot + 255)/256, 256, 0, stream>>>(W1, W2, W3, W1b, W2b, W3b);
    k_mlp    <<<GRID_MLP, 256, 0, stream>>>(aev, hdr, idx, W1b, W2b, W3b,
                                            b1, b2, b3, W4, b4, out);
}